// Round 4
// baseline (45.169 us; speedup 1.0000x reference)
//
#include <hip/hip_runtime.h>

#define FDIM 32
#define NNODES 255
#define NLEAVES 256
#define LOG2E 1.44269504088896340f

typedef _Float16 half8  __attribute__((ext_vector_type(8)));
typedef _Float16 half4v __attribute__((ext_vector_type(4)));
typedef _Float16 half2v __attribute__((ext_vector_type(2)));
typedef float    f32x4  __attribute__((ext_vector_type(4)));

__device__ __forceinline__ float fsig(float z) {
    // sigmoid(z) = 1/(1 + 2^(-z*log2e)); v_exp_f32 + v_rcp_f32
    return __builtin_amdgcn_rcpf(1.0f + __builtin_amdgcn_exp2f(-z * LOG2E));
}

// Prep: slot = node+1 (slot 0 dummy). Wh[slot][32] f16 relu'd weights,
// negc[slot] = -sum(relu(W)*sigmoid(S)), Dtab[y] = {cls[2y]-cls[2y+1], cls[2y+1]}.
__global__ void dtree_prep(const float* __restrict__ fi, const float* __restrict__ fs,
                           const float* __restrict__ cls,
                           _Float16* __restrict__ Wh, float* __restrict__ negc,
                           float* __restrict__ Dtab) {
    int t = threadIdx.x;   // 0..255
    if (t < 128) {
        float c0 = cls[2 * t], c1 = cls[2 * t + 1];
        Dtab[2 * t]     = c0 - c1;
        Dtab[2 * t + 1] = c1;
    }
    if (t == 0) {
#pragma unroll
        for (int k = 0; k < FDIM; ++k) Wh[k] = (_Float16)0.0f;
        negc[0] = 0.0f;
    } else {
        int node = t - 1;
        float s = 0.0f;
#pragma unroll
        for (int k = 0; k < FDIM; ++k) {
            float w = fi[(node << 5) + k];
            w = w > 0.0f ? w : 0.0f;
            Wh[(t << 5) + k] = (_Float16)w;
            s = fmaf(w, fsig(fs[(node << 5) + k]), s);
        }
        negc[t] = -s;
    }
}

// Fused kernel, 2 waves/block (fully independent; LDS is wave-private).
// Phase 1: 16 MFMAs (A=W rows=slots, B=x cols=samples, C-init=-c) -> sigmoid
//          -> f16 g into per-wave LDS [16 samples][264], 16B chunks XOR-swizzled
//          with c ^= (c>>3)&3 (identity for chunks < 8).
// Phase 2: tree walk, 4 lanes/sample x 4 subtrees/lane, vector LDS reads.
__global__ __launch_bounds__(128, 5) void dtree_fused(
    const float* __restrict__ x, const _Float16* __restrict__ Wh,
    const float* __restrict__ negc, const float* __restrict__ Dtab,
    float* __restrict__ out)
{
    __shared__ __align__(16) _Float16 gbuf[2][16][264];   // 16896 B

    const int tid = threadIdx.x;
    const int w = tid >> 6;          // wave in block (0/1)
    const int l = tid & 63;          // lane
    const int s = l & 15;            // sample col (phase1) / sample (phase2)
    const int h = l >> 4;            // 16-lane group
    const int n = blockIdx.x * 32 + w * 16 + s;

    // ---- Phase 1: B fragment = x[n][8h..8h+7] as f16 ----
    const float* xrow = x + (size_t)n * FDIM + 8 * h;
    f32x4 xv0 = *(const f32x4*)(xrow);
    f32x4 xv1 = *(const f32x4*)(xrow + 4);
    half8 bfrag;
    bfrag[0] = (_Float16)xv0[0]; bfrag[1] = (_Float16)xv0[1];
    bfrag[2] = (_Float16)xv0[2]; bfrag[3] = (_Float16)xv0[3];
    bfrag[4] = (_Float16)xv1[0]; bfrag[5] = (_Float16)xv1[1];
    bfrag[6] = (_Float16)xv1[2]; bfrag[7] = (_Float16)xv1[3];

    _Float16* gsw = &gbuf[w][s][0];

#pragma unroll
    for (int m = 0; m < 16; ++m) {
        // A fragment: row = l&15 -> slot = 16m + s ; k = 8h..8h+7
        half8 afrag = *(const half8*)(Wh + ((16 * m + s) << 5) + 8 * h);
        // C-in: -c for rows 16m+4h..+3 (C layout: row = 4h+r, col = s)
        f32x4 cin = *(const f32x4*)(negc + 16 * m + 4 * h);
        f32x4 acc = __builtin_amdgcn_mfma_f32_16x16x32_f16(afrag, bfrag, cin, 0, 0, 0);
        half4v hg;
        hg[0] = (_Float16)fsig(acc[0]);
        hg[1] = (_Float16)fsig(acc[1]);
        hg[2] = (_Float16)fsig(acc[2]);
        hg[3] = (_Float16)fsig(acc[3]);
        // logical 16B chunk cw = 2m + (h>>1); physical = cw ^ ((cw>>3)&3)
        int cw = 2 * m + (h >> 1);
        int cw2 = cw ^ ((cw >> 3) & 3);
        *(half4v*)(gsw + cw2 * 8 + (h & 1) * 4) = hg;
    }

    // Wave-private producer->consumer through LDS: wave-local wait only.
    asm volatile("s_waitcnt lgkmcnt(0)" ::: "memory");
    __builtin_amdgcn_sched_barrier(0);

    // ---- Phase 2: walk. lane handles sample s, subtrees i = 4h+j (j=0..3) ----
    const _Float16* gs = gsw;
    float g1  = (float)gs[1];                         // root (level 0)
    float gP2 = (float)gs[2 + (h >> 1)];              // level 1, slot 2+(i>>3)
    float gP3 = (float)gs[4 + h];                     // level 2, slot 4+(i>>2)=4+h
    half2v p4p = *(const half2v*)(gs + 8 + 2 * h);    // level 3 slots 8+2h, 9+2h
    float gP4a = (float)p4p[0], gP4b = (float)p4p[1];
    half4v dDv = *(const half4v*)(gs + 16 + 4 * h);   // level 4: slots 16+4h..+3
    half8  dEv = *(const half8*)(gs + 32 + 8 * h);    // level 5: slots 32+8h..+7
    // level 6 (16 slots 64+16h..+15): logical chunks 8+2h / 9+2h, swizzle swaps
    half8  dF0 = *(const half8*)(gs + (9 + 2 * h) * 8);
    half8  dF1 = *(const half8*)(gs + (8 + 2 * h) * 8);

    float f0 = (h & 2) ? 1.0f - g1  : g1;             // bit0 of leaf-prefix = i>>3
    float f1 = (h & 1) ? 1.0f - gP2 : gP2;            // bit1 = (i>>2)&1 = h&1
    float f01 = f0 * f1;

    const f32x4* dtb = (const f32x4*)Dtab;
    float facc = 0.0f;

#pragma unroll
    for (int j = 0; j < 4; ++j) {                     // i = 4h + j
        float f2 = (j & 2) ? 1.0f - gP3 : gP3;        // bit2 = (i>>1)&1 = j>>1
        float gP4 = (j & 2) ? gP4b : gP4a;            // slot 8+(i>>1)
        float f3 = (j & 1) ? 1.0f - gP4 : gP4;        // bit3 = i&1 = j&1
        float p4 = f01 * (f2 * f3);
        float gD = (float)dDv[j];                     // slot 16+i
        // level 7 slots 128+8i..+7: logical chunk 16+4h+j, swizzled
        int cg = (16 + 4 * h + j) ^ (2 + (h >> 1));
        half8 dG = *(const half8*)(gs + cg * 8);
        f32x4 q0 = dtb[16 * h + 4 * j + 0];           // leaf-pair table y=8i..8i+7
        f32x4 q1 = dtb[16 * h + 4 * j + 1];
        f32x4 q2 = dtb[16 * h + 4 * j + 2];
        f32x4 q3 = dtb[16 * h + 4 * j + 3];
#pragma unroll
        for (int b4 = 0; b4 < 2; ++b4) {
            float p5 = b4 ? (p4 - p4 * gD) : (p4 * gD);
            float gE = (float)dEv[2 * j + b4];        // slot 32+2i+b4
#pragma unroll
            for (int b5 = 0; b5 < 2; ++b5) {
                float p6 = b5 ? (p5 - p5 * gE) : (p5 * gE);
                float gF = (float)((j & 2) ? dF1[4 * (j & 1) + 2 * b4 + b5]
                                           : dF0[4 * (j & 1) + 2 * b4 + b5]);
#pragma unroll
                for (int b6 = 0; b6 < 2; ++b6) {
                    float p7 = b6 ? (p6 - p6 * gF) : (p6 * gF);
                    int t = 4 * b4 + 2 * b5 + b6;     // static
                    float gG = (float)dG[t];
                    f32x4 q = (t < 2) ? q0 : (t < 4) ? q1 : (t < 6) ? q2 : q3;
                    float D0 = (t & 1) ? q[2] : q[0];
                    float D1 = (t & 1) ? q[3] : q[1];
                    facc = fmaf(p7, fmaf(gG, D0, D1), facc);
                }
            }
        }
    }

    // combine the 4 h-lanes of each sample
    facc += __shfl_xor(facc, 16, 64);
    facc += __shfl_xor(facc, 32, 64);
    if (h == 0) out[n] = facc;
}

extern "C" void kernel_launch(void* const* d_in, const int* in_sizes, int n_in,
                              void* d_out, int out_size, void* d_ws, size_t ws_size,
                              hipStream_t stream) {
    const float* x   = (const float*)d_in[0];
    const float* fi  = (const float*)d_in[1];
    const float* fs  = (const float*)d_in[2];
    const float* cls = (const float*)d_in[3];

    _Float16* Wh = (_Float16*)d_ws;                        // 256*32*2 = 16 KB
    float* negc  = (float*)((char*)d_ws + 16384);          // 1 KB
    float* Dtab  = negc + 256;                             // 1 KB

    int nsamp = in_sizes[0] / FDIM;                        // 262144
    float* out = (float*)d_out;

    hipLaunchKernelGGL(dtree_prep, dim3(1), dim3(256), 0, stream, fi, fs, cls, Wh, negc, Dtab);
    hipLaunchKernelGGL(dtree_fused, dim3(nsamp / 32), dim3(128), 0, stream,
                       x, Wh, negc, Dtab, out);
}

// Round 5
// 33.282 us; speedup vs baseline: 1.3572x; 1.3572x over previous
//
#include <hip/hip_runtime.h>

#define FDIM 32
#define LOG2E 1.44269504088896340f

typedef _Float16 half8 __attribute__((ext_vector_type(8)));
typedef float    f32x4 __attribute__((ext_vector_type(4)));
typedef float    f32x2 __attribute__((ext_vector_type(2)));

__device__ __forceinline__ float fsig(float z) {
    // sigmoid(z) = 1/(1 + 2^(-z*log2e)); v_exp_f32 + v_rcp_f32
    return __builtin_amdgcn_rcpf(1.0f + __builtin_amdgcn_exp2f(-z * LOG2E));
}

// Row-permutation: MFMA A-row rho = 16m + 4h + r  ->  tree slot (slot = node+1,
// heap: root=1, children of q are 2q/2q+1; level d = slots 2^d..2^(d+1)-1).
// Chosen so lane (s,h)'s 64 accumulator values are exactly the nodes its
// phase-2 walk needs (levels 4-7 of subtrees i=4h..4h+3), h-uniformly indexed:
//   m=0          -> path slots 1+4h+r   (h==3,r==3 -> dummy slot 0)
//   m=1          -> L4: 16+4h+r
//   m=2..3       -> L5: 32+8h+2*(2(m-2)+(r>>1)) + (r&1)
//   m=4..7       -> L6: 64+16h+4(m-4)+r
//   m=8..15      -> L7: 128+32h+8*((m-8)>>1) + 4*((m-8)&1) + r
__device__ __forceinline__ int row_to_slot(int rho) {
    int m = rho >> 4, h = (rho >> 2) & 3, r = rho & 3;
    if (m == 0)      return (h == 3 && r == 3) ? 0 : 1 + 4 * h + r;
    if (m == 1)      return 16 + 4 * h + r;
    if (m <= 3)      return 32 + 8 * h + 2 * (2 * (m - 2) + (r >> 1)) + (r & 1);
    if (m <= 7)      return 64 + 16 * h + 4 * (m - 4) + r;
    return 128 + 32 * h + 8 * ((m - 8) >> 1) + 4 * ((m - 8) & 1) + r;
}

// Prep: Wh[rho][32] = relu(fi[slot-1]) in f16 (permuted rows), negc[rho] =
// -sum(relu(W)*sigmoid(S)) of that node, Dtab[y] = {cls[2y]-cls[2y+1], cls[2y+1]}.
__global__ void dtree_prep(const float* __restrict__ fi, const float* __restrict__ fs,
                           const float* __restrict__ cls,
                           _Float16* __restrict__ Wh, float* __restrict__ negc,
                           float* __restrict__ Dtab) {
    int t = threadIdx.x;   // 0..255 = permuted row rho
    if (t < 128) {
        float c0 = cls[2 * t], c1 = cls[2 * t + 1];
        Dtab[2 * t]     = c0 - c1;
        Dtab[2 * t + 1] = c1;
    }
    int slot = row_to_slot(t);
    if (slot == 0) {
#pragma unroll
        for (int k = 0; k < FDIM; ++k) Wh[(t << 5) + k] = (_Float16)0.0f;
        negc[t] = 0.0f;
    } else {
        int node = slot - 1;
        float s = 0.0f;
#pragma unroll
        for (int k = 0; k < FDIM; ++k) {
            float w = fi[(node << 5) + k];
            w = w > 0.0f ? w : 0.0f;
            Wh[(t << 5) + k] = (_Float16)w;
            s = fmaf(w, fsig(fs[(node << 5) + k]), s);
        }
        negc[t] = -s;
    }
}

// Fused: 2 independent waves/block, 16 samples/wave. 16 MFMAs with permuted W
// put each lane's needed subtree g's straight into its accumulators; sigmoid
// in-register (f32); only 15 path values/sample bounce through LDS.
__global__ __launch_bounds__(128, 4) void dtree_fused(
    const float* __restrict__ x, const _Float16* __restrict__ Wh,
    const float* __restrict__ negc, const float* __restrict__ Dtab,
    float* __restrict__ out)
{
    __shared__ __align__(16) float sNegc[256];        // 1 KB, broadcast reads
    __shared__ __align__(16) float sDtab[256];        // 1 KB, broadcast reads
    __shared__ __align__(16) float pbuf[2][16][20];   // 2.5 KB path exchange

    const int tid = threadIdx.x;
    const int w = tid >> 6;          // wave in block (0/1)
    const int l = tid & 63;
    const int s = l & 15;            // sample col
    const int h = l >> 4;            // 16-lane group
    const int n = blockIdx.x * 32 + w * 16 + s;

    if (tid < 64)        ((f32x4*)sNegc)[tid]      = ((const f32x4*)negc)[tid];
    else if (tid < 128)  ((f32x4*)sDtab)[tid - 64] = ((const f32x4*)Dtab)[tid - 64];
    __syncthreads();

    // B fragment: x[n][8h..8h+7] as f16
    const float* xrow = x + (size_t)n * FDIM + 8 * h;
    f32x4 xv0 = *(const f32x4*)(xrow);
    f32x4 xv1 = *(const f32x4*)(xrow + 4);
    half8 bfrag;
    bfrag[0] = (_Float16)xv0[0]; bfrag[1] = (_Float16)xv0[1];
    bfrag[2] = (_Float16)xv0[2]; bfrag[3] = (_Float16)xv0[3];
    bfrag[4] = (_Float16)xv1[0]; bfrag[5] = (_Float16)xv1[1];
    bfrag[6] = (_Float16)xv1[2]; bfrag[7] = (_Float16)xv1[3];

    // Phase 1: 16 MFMAs; lane (s,h) gets rows 16m+4h+r of permuted g for its
    // own sample s. Sigmoid applied in-register; g stays f32.
    float gm[16][4];   // all indices compile-time after full unroll
#pragma unroll
    for (int m = 0; m < 16; ++m) {
        half8 afrag = *(const half8*)(Wh + ((16 * m + s) << 5) + 8 * h);
        f32x4 cin = *(const f32x4*)(sNegc + 16 * m + 4 * h);   // LDS broadcast
        f32x4 acc = __builtin_amdgcn_mfma_f32_16x16x32_f16(afrag, bfrag, cin, 0, 0, 0);
        gm[m][0] = fsig(acc[0]);
        gm[m][1] = fsig(acc[1]);
        gm[m][2] = fsig(acc[2]);
        gm[m][3] = fsig(acc[3]);
        if (m == 0) {   // path slots 1+4h+r -> pbuf[w][s][4h+r]
            f32x4 pv;
            pv[0] = gm[0][0]; pv[1] = gm[0][1]; pv[2] = gm[0][2]; pv[3] = gm[0][3];
            *(f32x4*)(&pbuf[w][s][4 * h]) = pv;
        }
    }

    // Wave-private cross-lane exchange: wave-local wait + scheduler fence (rule 18).
    asm volatile("s_waitcnt lgkmcnt(0)" ::: "memory");
    __builtin_amdgcn_sched_barrier(0);

    const float* pb = &pbuf[w][s][0];
    float g1   = pb[0];                 // slot 1 (root)
    float gP2  = pb[1 + (h >> 1)];      // slot 2+(h>>1)  (level 1)
    float gP3  = pb[3 + h];             // slot 4+h       (level 2)
    float gP4a = pb[7 + 2 * h];         // slot 8+2h      (level 3)
    float gP4b = pb[8 + 2 * h];         // slot 9+2h

    float f0 = (h & 2) ? 1.0f - g1  : g1;    // leaf bit0 = i>>3 = h>>1... (h&2)
    float f1 = (h & 1) ? 1.0f - gP2 : gP2;   // leaf bit1 = (i>>2)&1 = h&1
    float f01 = f0 * f1;

    const float* dtb = sDtab + 64 * h;       // leaf-pair table, y = 8i+t
    float facc = 0.0f;

#pragma unroll
    for (int j = 0; j < 4; ++j) {            // subtree i = 4h + j
        float f2  = (j & 2) ? 1.0f - gP3 : gP3;       // bit2 = (j>>1)&1
        float gP4 = (j & 2) ? gP4b : gP4a;            // slot 8+2h+(j>>1)
        float f3  = (j & 1) ? 1.0f - gP4 : gP4;       // bit3 = j&1
        float p4  = f01 * (f2 * f3);
        float gD  = gm[1][j];                          // L4: slot 16+4h+j
#pragma unroll
        for (int b4 = 0; b4 < 2; ++b4) {
            float p5 = b4 ? (p4 - p4 * gD) : (p4 * gD);
            float gE = gm[2 + (j >> 1)][2 * (j & 1) + b4];   // L5: 32+8h+2j+b4
#pragma unroll
            for (int b5 = 0; b5 < 2; ++b5) {
                float p6 = b5 ? (p5 - p5 * gE) : (p5 * gE);
                float gF = gm[4 + j][2 * b4 + b5];           // L6: 64+16h+4j+..
#pragma unroll
                for (int b6 = 0; b6 < 2; ++b6) {
                    float p7 = b6 ? (p6 - p6 * gF) : (p6 * gF);
                    int t = 4 * b4 + 2 * b5 + b6;            // static
                    float gG = gm[8 + 2 * j + (t >> 2)][t & 3]; // L7: 128+32h+8j+t
                    f32x2 Dp = *(const f32x2*)(dtb + 16 * j + 2 * t); // {c0-c1,c1}
                    facc = fmaf(p7, fmaf(gG, Dp[0], Dp[1]), facc);
                }
            }
        }
    }

    // combine the 4 h-lanes of each sample
    facc += __shfl_xor(facc, 16, 64);
    facc += __shfl_xor(facc, 32, 64);
    if (h == 0) out[n] = facc;
}

extern "C" void kernel_launch(void* const* d_in, const int* in_sizes, int n_in,
                              void* d_out, int out_size, void* d_ws, size_t ws_size,
                              hipStream_t stream) {
    const float* x   = (const float*)d_in[0];
    const float* fi  = (const float*)d_in[1];
    const float* fs  = (const float*)d_in[2];
    const float* cls = (const float*)d_in[3];

    _Float16* Wh = (_Float16*)d_ws;                        // 256*32*2 = 16 KB
    float* negc  = (float*)((char*)d_ws + 16384);          // 1 KB
    float* Dtab  = negc + 256;                             // 1 KB

    int nsamp = in_sizes[0] / FDIM;                        // 262144
    float* out = (float*)d_out;

    hipLaunchKernelGGL(dtree_prep, dim3(1), dim3(256), 0, stream, fi, fs, cls, Wh, negc, Dtab);
    hipLaunchKernelGGL(dtree_fused, dim3(nsamp / 32), dim3(128), 0, stream,
                       x, Wh, negc, Dtab, out);
}